// Round 1
// 184.946 us; speedup vs baseline: 1.0055x; 1.0055x over previous
//
#include <hip/hip_runtime.h>
#include <hip/hip_bf16.h>

// Bilinear: out[s,i,j] = sum_{d,e} t1[s,i,d] * K[d,e] * t0[s,j,e] + bias
// S=8, N=2048, D=256.
// bf16 MFMA, two NT GEMMs:
//   Q[s,j,d]   = sum_e t0[s,j,e] * K[d,e]         (prep, bf16 out)
//   out[s,i,j] = sum_d t1[s,i,d] * Q[s,j,d] + b   (main, fp32 out)
// R3: BK=64 ping-pong double-buffer (was BK=32) -> 4 barrier/drain phases per
// block instead of 8, 32-MFMA clusters per phase. [128][64] bf16 tiles have a
// 128B row stride (16-way bank conflict on ds_read_b128), so we XOR-swizzle
// the 16B slot with (row&7): LDS dest stays linear (global_load_lds rule),
// the per-lane GLOBAL source column is pre-swizzled, and reads apply the same
// XOR -> identity composition, conflict-free (8 lanes per slot, uniform).

typedef __bf16 bf16x8 __attribute__((ext_vector_type(8)));
typedef float f32x4 __attribute__((ext_vector_type(4)));

__device__ __forceinline__ unsigned short f2bf(float f) {
  union { __hip_bfloat16 h; unsigned short u; } v;
  v.h = __float2bfloat16(f);
  return v.u;
}

// Convert t0 (4M), t1 (4M), kernel (64K) fp32 -> bf16 into workspace.
__global__ __launch_bounds__(256) void cvt3(const float4* __restrict__ t0,
                                            const float4* __restrict__ t1,
                                            const float4* __restrict__ kk,
                                            ushort4* __restrict__ o0,
                                            ushort4* __restrict__ o1,
                                            ushort4* __restrict__ ok) {
  const int stride = gridDim.x * blockDim.x;
  const int i0 = blockIdx.x * blockDim.x + threadIdx.x;
  for (int j = i0; j < 1048576; j += stride) {
    float4 v = t0[j];
    o0[j] = make_ushort4(f2bf(v.x), f2bf(v.y), f2bf(v.z), f2bf(v.w));
  }
  for (int j = i0; j < 1048576; j += stride) {
    float4 v = t1[j];
    o1[j] = make_ushort4(f2bf(v.x), f2bf(v.y), f2bf(v.z), f2bf(v.w));
  }
  for (int j = i0; j < 16384; j += stride) {
    float4 v = kk[j];
    ok[j] = make_ushort4(f2bf(v.x), f2bf(v.y), f2bf(v.z), f2bf(v.w));
  }
}

// NT GEMM: C[m][n] = sum_k A[m][k]*B[n][k] (+bias), A,B bf16 row-major [rows][K].
// 128x128 tile, BK=64 ping-pong, 256 threads = 4 waves, each wave a 64x64
// subtile of 4x4 mfma_f32_16x16x32_bf16. K must be a multiple of 64.
template <bool OUT_BF16>
__global__ __launch_bounds__(256, 2) void gemm_nt(
    const unsigned short* __restrict__ A, const unsigned short* __restrict__ B,
    void* __restrict__ Cout, const float* __restrict__ bias,
    const int K, const int ldc,
    const long long aStride, const long long bStride, const long long cStride) {
  // [128][64] swizzled tiles, double-buffered: 2*(16+16) = 64 KiB -> 2 blk/CU
  __shared__ unsigned short sA[2][128 * 64];
  __shared__ unsigned short sB[2][128 * 64];

  const int tid = threadIdx.x;
  const int wave = tid >> 6;
  const int lane = tid & 63;
  const int quad = lane >> 4;
  const int l16 = lane & 15;
  const int wrow = (wave >> 1) * 64;  // wave's 64x64 subtile origin
  const int wcol = (wave & 1) * 64;
  const int rsw = (l16 & 7) * 8;      // read-side XOR swizzle (elements)

  const int brow = blockIdx.y * 128;
  const int bcol = blockIdx.x * 128;
  const long long bz = blockIdx.z;

  const unsigned short* Ab = A + bz * aStride + (long long)brow * K;
  const unsigned short* Bb = B + bz * bStride + (long long)bcol * K;

  // staging: lane -> (rowgroup + lane>>3, 16B-slot lane&7). LDS dest is
  // wave-uniform base + lane*16B (linear row-major [128][64]); the GLOBAL
  // source column is pre-swizzled with the same involution the reads use,
  // so physical slot p of row r holds logical slot p ^ (r&7).
  const int srow = lane >> 3;                   // 0..7 within 8-row group
  const int scol = ((lane & 7) ^ srow) * 8;     // pre-swizzled col (elements)

  auto stage = [&](unsigned short* dA, unsigned short* dB, int kt) {
#pragma unroll
    for (int i = 0; i < 4; i++) {
      const int r = i * 32 + wave * 8;          // 8-row group base (mult of 8)
      const unsigned short* ga = Ab + (long long)(r + srow) * K + kt + scol;
      const unsigned short* gb = Bb + (long long)(r + srow) * K + kt + scol;
      __builtin_amdgcn_global_load_lds(
          (const __attribute__((address_space(1))) unsigned int*)ga,
          (__attribute__((address_space(3))) unsigned int*)(dA + r * 64),
          16, 0, 0);
      __builtin_amdgcn_global_load_lds(
          (const __attribute__((address_space(1))) unsigned int*)gb,
          (__attribute__((address_space(3))) unsigned int*)(dB + r * 64),
          16, 0, 0);
    }
  };

  f32x4 acc[4][4];
#pragma unroll
  for (int i = 0; i < 4; i++)
#pragma unroll
    for (int j = 0; j < 4; j++) acc[i][j] = (f32x4){0.f, 0.f, 0.f, 0.f};

  stage(sA[0], sB[0], 0);  // prologue: tile 0 in flight; acc-init overlaps

  int cur = 0;
  for (int kt = 0; kt < K; kt += 64) {
    __syncthreads();  // drains vmcnt: buf[cur] staged; prior buf reads done
    const unsigned short* a = sA[cur];
    const unsigned short* b = sB[cur];
    // ---- kk = 0 half (cols 0..31 of the 64-deep tile) ----
    {
      bf16x8 af[4], bfr[4];
#pragma unroll
      for (int mi = 0; mi < 4; mi++) {
        const int row = wrow + mi * 16 + l16;   // row&7 == l16&7
        af[mi] = *(const bf16x8*)&a[row * 64 + ((quad * 8) ^ rsw)];
      }
#pragma unroll
      for (int ni = 0; ni < 4; ni++) {
        const int row = wcol + ni * 16 + l16;
        bfr[ni] = *(const bf16x8*)&b[row * 64 + ((quad * 8) ^ rsw)];
      }
      if (kt + 64 < K) stage(sA[cur ^ 1], sB[cur ^ 1], kt + 64);
#pragma unroll
      for (int mi = 0; mi < 4; mi++)
#pragma unroll
        for (int ni = 0; ni < 4; ni++)
          acc[mi][ni] = __builtin_amdgcn_mfma_f32_16x16x32_bf16(
              af[mi], bfr[ni], acc[mi][ni], 0, 0, 0);
    }
    // ---- kk = 1 half (cols 32..63) ----
    {
      bf16x8 af[4], bfr[4];
#pragma unroll
      for (int mi = 0; mi < 4; mi++) {
        const int row = wrow + mi * 16 + l16;
        af[mi] = *(const bf16x8*)&a[row * 64 + ((32 + quad * 8) ^ rsw)];
      }
#pragma unroll
      for (int ni = 0; ni < 4; ni++) {
        const int row = wcol + ni * 16 + l16;
        bfr[ni] = *(const bf16x8*)&b[row * 64 + ((32 + quad * 8) ^ rsw)];
      }
#pragma unroll
      for (int mi = 0; mi < 4; mi++)
#pragma unroll
        for (int ni = 0; ni < 4; ni++)
          acc[mi][ni] = __builtin_amdgcn_mfma_f32_16x16x32_bf16(
              af[mi], bfr[ni], acc[mi][ni], 0, 0, 0);
    }
    cur ^= 1;
  }

  // C/D frag mapping (m89-verified): col = lane&15, row = quad*4 + reg
  if constexpr (OUT_BF16) {
    unsigned short* C = (unsigned short*)Cout + bz * cStride;
#pragma unroll
    for (int mi = 0; mi < 4; mi++)
#pragma unroll
      for (int ni = 0; ni < 4; ni++) {
        const int r0 = brow + wrow + mi * 16 + quad * 4;
        const int c = bcol + wcol + ni * 16 + l16;
#pragma unroll
        for (int r = 0; r < 4; r++)
          C[(long long)(r0 + r) * ldc + c] = f2bf(acc[mi][ni][r]);
      }
  } else {
    const float bv = bias[0];
    float* C = (float*)Cout + bz * cStride;
#pragma unroll
    for (int mi = 0; mi < 4; mi++)
#pragma unroll
      for (int ni = 0; ni < 4; ni++) {
        const int r0 = brow + wrow + mi * 16 + quad * 4;
        const int c = bcol + wcol + ni * 16 + l16;
#pragma unroll
        for (int r = 0; r < 4; r++)
          C[(long long)(r0 + r) * ldc + c] = acc[mi][ni][r] + bv;
      }
  }
}

extern "C" void kernel_launch(void* const* d_in, const int* in_sizes, int n_in,
                              void* d_out, int out_size, void* d_ws, size_t ws_size,
                              hipStream_t stream) {
  const float* t0 = (const float*)d_in[0];    // [8,2048,256]
  const float* t1 = (const float*)d_in[1];    // [8,2048,256]
  const float* kk = (const float*)d_in[2];    // [256,256]
  const float* bias = (const float*)d_in[3];  // [1]

  // ws layout (bf16 elements): T0b 4M | T1b 4M | Kb 64K | Qb 4M  = 24.2 MiB
  unsigned short* T0b = (unsigned short*)d_ws;
  unsigned short* T1b = T0b + 4194304;
  unsigned short* Kb = T1b + 4194304;
  unsigned short* Qb = Kb + 65536;

  cvt3<<<4096, 256, 0, stream>>>((const float4*)t0, (const float4*)t1,
                                 (const float4*)kk, (ushort4*)T0b,
                                 (ushort4*)T1b, (ushort4*)Kb);

  // Q[s*N+j][d] = sum_e t0[s,j,e]*K[d,e]  : M=16384, N=256, K=256
  gemm_nt<true><<<dim3(2, 128, 1), 256, 0, stream>>>(T0b, Kb, Qb, nullptr, 256,
                                                     256, 0, 0, 0);

  // out[s][i][j] = sum_d t1[s,i,d]*Q[s,j,d] + bias : per-s 2048x2048, K=256
  gemm_nt<false><<<dim3(16, 16, 8), 256, 0, stream>>>(
      T1b, Qb, d_out, bias, 256, 2048, 524288LL, 524288LL, 4194304LL);
}

// Round 2
// 180.261 us; speedup vs baseline: 1.0316x; 1.0260x over previous
//
#include <hip/hip_runtime.h>
#include <hip/hip_bf16.h>

// Bilinear: out[s,i,j] = sum_{d,e} t1[s,i,d] * K[d,e] * t0[s,j,e] + bias
// S=8, N=2048, D=256.
// R4: two launches instead of three.
//   prep (fused): blocks 0..255   = gemm1 Q[s*N+j][d] = sum_e t0*K, reading
//                                   FP32 t0/K directly (reg-stage + convert)
//                 blocks 256..1279 = t1 fp32->bf16 conversion (fills idle CUs)
//   gemm_nt<false>: out[s][i][j] = sum_d t1[s,i,d]*Q[s,j,d] + bias
// GEMM structure: 128x128 tile, BK=64 ping-pong double-buffer, 4 waves,
// [128][64] bf16 LDS tiles with (row&7) XOR-swizzle on the 16B slot
// (pre-swizzled source + swizzled read = identity, conflict-free b128).

typedef __bf16 bf16x8 __attribute__((ext_vector_type(8)));
typedef float f32x4 __attribute__((ext_vector_type(4)));

__device__ __forceinline__ unsigned short f2bf(float f) {
  union { __hip_bfloat16 h; unsigned short u; } v;
  v.h = __float2bfloat16(f);
  return v.u;
}

// load 8 fp32, convert, store 8 bf16 (16B) -> LDS as one ds_write_b128
__device__ __forceinline__ void cvt8_store(unsigned short* dst, const float* src) {
  float4 v0 = *(const float4*)src;
  float4 v1 = *(const float4*)(src + 4);
  union { unsigned short u[8]; uint4 q; } p;
  p.u[0] = f2bf(v0.x); p.u[1] = f2bf(v0.y); p.u[2] = f2bf(v0.z); p.u[3] = f2bf(v0.w);
  p.u[4] = f2bf(v1.x); p.u[5] = f2bf(v1.y); p.u[6] = f2bf(v1.z); p.u[7] = f2bf(v1.w);
  *(uint4*)dst = p.q;
}

// Fused prep: gemm1 (fp32-in, bf16-out) on blocks 0..255; t1 cvt on 256..1279.
__global__ __launch_bounds__(256, 2) void prep(
    const float* __restrict__ t0, const float4* __restrict__ t1,
    const float* __restrict__ kk, ushort4* __restrict__ T1b,
    unsigned short* __restrict__ Qb) {
  const int tid = threadIdx.x;

  if (blockIdx.x >= 256) {
    // ---- t1 fp32 -> bf16: 1024 blocks x 256 thr x 4 iters = 1M float4 ----
    const int i0 = (blockIdx.x - 256) * 256 + tid;
#pragma unroll
    for (int it = 0; it < 4; it++) {
      const int j = i0 + it * 262144;
      float4 v = t1[j];
      T1b[j] = make_ushort4(f2bf(v.x), f2bf(v.y), f2bf(v.z), f2bf(v.w));
    }
    return;
  }

  // ---- gemm1: Q[m][n] = sum_k t0[m][k] * K[n][k], M=16384 N=256 K=256 ----
  __shared__ unsigned short sA[2][128 * 64];
  __shared__ unsigned short sB[2][128 * 64];

  const int wave = tid >> 6;
  const int lane = tid & 63;
  const int quad = lane >> 4;
  const int l16 = lane & 15;
  const int wrow = (wave >> 1) * 64;
  const int wcol = (wave & 1) * 64;
  const int rsw = (l16 & 7) * 8;  // read-side XOR swizzle (elements)

  const int brow = (blockIdx.x >> 1) * 128;
  const int bcol = (blockIdx.x & 1) * 128;

  const float* Af = t0 + (long long)brow * 256;
  const float* Bf = kk + (long long)bcol * 256;

  const int srow = lane >> 3;                // row within 8-row group
  const int scol = ((lane & 7) ^ srow) * 8;  // pre-swizzled source col (elems)

  auto stage1 = [&](unsigned short* dA, unsigned short* dB, int kt) {
#pragma unroll
    for (int i = 0; i < 4; i++) {
      const int rr = i * 32 + wave * 8 + srow;
      cvt8_store(dA + rr * 64 + (lane & 7) * 8,
                 Af + (long long)rr * 256 + kt + scol);
      cvt8_store(dB + rr * 64 + (lane & 7) * 8,
                 Bf + (long long)rr * 256 + kt + scol);
    }
  };

  f32x4 acc[4][4];
#pragma unroll
  for (int i = 0; i < 4; i++)
#pragma unroll
    for (int j = 0; j < 4; j++) acc[i][j] = (f32x4){0.f, 0.f, 0.f, 0.f};

  stage1(sA[0], sB[0], 0);

  int cur = 0;
  for (int kt = 0; kt < 256; kt += 64) {
    __syncthreads();
    const unsigned short* a = sA[cur];
    const unsigned short* b = sB[cur];
    bf16x8 af[4], bfr[4];
#pragma unroll
    for (int mi = 0; mi < 4; mi++)
      af[mi] = *(const bf16x8*)&a[(wrow + mi * 16 + l16) * 64 + ((quad * 8) ^ rsw)];
#pragma unroll
    for (int ni = 0; ni < 4; ni++)
      bfr[ni] = *(const bf16x8*)&b[(wcol + ni * 16 + l16) * 64 + ((quad * 8) ^ rsw)];
    if (kt + 64 < 256) stage1(sA[cur ^ 1], sB[cur ^ 1], kt + 64);
#pragma unroll
    for (int mi = 0; mi < 4; mi++)
#pragma unroll
      for (int ni = 0; ni < 4; ni++)
        acc[mi][ni] = __builtin_amdgcn_mfma_f32_16x16x32_bf16(
            af[mi], bfr[ni], acc[mi][ni], 0, 0, 0);
#pragma unroll
    for (int mi = 0; mi < 4; mi++)
      af[mi] = *(const bf16x8*)&a[(wrow + mi * 16 + l16) * 64 + ((32 + quad * 8) ^ rsw)];
#pragma unroll
    for (int ni = 0; ni < 4; ni++)
      bfr[ni] = *(const bf16x8*)&b[(wcol + ni * 16 + l16) * 64 + ((32 + quad * 8) ^ rsw)];
#pragma unroll
    for (int mi = 0; mi < 4; mi++)
#pragma unroll
      for (int ni = 0; ni < 4; ni++)
        acc[mi][ni] = __builtin_amdgcn_mfma_f32_16x16x32_bf16(
            af[mi], bfr[ni], acc[mi][ni], 0, 0, 0);
    cur ^= 1;
  }

  // C/D frag mapping (m89-verified): col = lane&15, row = quad*4 + reg
#pragma unroll
  for (int mi = 0; mi < 4; mi++)
#pragma unroll
    for (int ni = 0; ni < 4; ni++) {
      const int r0 = brow + wrow + mi * 16 + quad * 4;
      const int c = bcol + wcol + ni * 16 + l16;
#pragma unroll
      for (int r = 0; r < 4; r++)
        Qb[(long long)(r0 + r) * 256 + c] = f2bf(acc[mi][ni][r]);
    }
}

// NT GEMM: C[m][n] = sum_k A[m][k]*B[n][k] (+bias), A,B bf16 row-major [rows][K].
// 128x128 tile, BK=64 ping-pong, 256 threads = 4 waves, each wave a 64x64
// subtile of 4x4 mfma_f32_16x16x32_bf16. K must be a multiple of 64.
template <bool OUT_BF16>
__global__ __launch_bounds__(256, 2) void gemm_nt(
    const unsigned short* __restrict__ A, const unsigned short* __restrict__ B,
    void* __restrict__ Cout, const float* __restrict__ bias,
    const int K, const int ldc,
    const long long aStride, const long long bStride, const long long cStride) {
  __shared__ unsigned short sA[2][128 * 64];
  __shared__ unsigned short sB[2][128 * 64];

  const int tid = threadIdx.x;
  const int wave = tid >> 6;
  const int lane = tid & 63;
  const int quad = lane >> 4;
  const int l16 = lane & 15;
  const int wrow = (wave >> 1) * 64;
  const int wcol = (wave & 1) * 64;
  const int rsw = (l16 & 7) * 8;

  const int brow = blockIdx.y * 128;
  const int bcol = blockIdx.x * 128;
  const long long bz = blockIdx.z;

  const unsigned short* Ab = A + bz * aStride + (long long)brow * K;
  const unsigned short* Bb = B + bz * bStride + (long long)bcol * K;

  const int srow = lane >> 3;
  const int scol = ((lane & 7) ^ srow) * 8;

  auto stage = [&](unsigned short* dA, unsigned short* dB, int kt) {
#pragma unroll
    for (int i = 0; i < 4; i++) {
      const int r = i * 32 + wave * 8;
      const unsigned short* ga = Ab + (long long)(r + srow) * K + kt + scol;
      const unsigned short* gb = Bb + (long long)(r + srow) * K + kt + scol;
      __builtin_amdgcn_global_load_lds(
          (const __attribute__((address_space(1))) unsigned int*)ga,
          (__attribute__((address_space(3))) unsigned int*)(dA + r * 64),
          16, 0, 0);
      __builtin_amdgcn_global_load_lds(
          (const __attribute__((address_space(1))) unsigned int*)gb,
          (__attribute__((address_space(3))) unsigned int*)(dB + r * 64),
          16, 0, 0);
    }
  };

  f32x4 acc[4][4];
#pragma unroll
  for (int i = 0; i < 4; i++)
#pragma unroll
    for (int j = 0; j < 4; j++) acc[i][j] = (f32x4){0.f, 0.f, 0.f, 0.f};

  stage(sA[0], sB[0], 0);

  int cur = 0;
  for (int kt = 0; kt < K; kt += 64) {
    __syncthreads();
    const unsigned short* a = sA[cur];
    const unsigned short* b = sB[cur];
    {
      bf16x8 af[4], bfr[4];
#pragma unroll
      for (int mi = 0; mi < 4; mi++)
        af[mi] = *(const bf16x8*)&a[(wrow + mi * 16 + l16) * 64 + ((quad * 8) ^ rsw)];
#pragma unroll
      for (int ni = 0; ni < 4; ni++)
        bfr[ni] = *(const bf16x8*)&b[(wcol + ni * 16 + l16) * 64 + ((quad * 8) ^ rsw)];
      if (kt + 64 < K) stage(sA[cur ^ 1], sB[cur ^ 1], kt + 64);
#pragma unroll
      for (int mi = 0; mi < 4; mi++)
#pragma unroll
        for (int ni = 0; ni < 4; ni++)
          acc[mi][ni] = __builtin_amdgcn_mfma_f32_16x16x32_bf16(
              af[mi], bfr[ni], acc[mi][ni], 0, 0, 0);
    }
    {
      bf16x8 af[4], bfr[4];
#pragma unroll
      for (int mi = 0; mi < 4; mi++)
        af[mi] = *(const bf16x8*)&a[(wrow + mi * 16 + l16) * 64 + ((32 + quad * 8) ^ rsw)];
#pragma unroll
      for (int ni = 0; ni < 4; ni++)
        bfr[ni] = *(const bf16x8*)&b[(wcol + ni * 16 + l16) * 64 + ((32 + quad * 8) ^ rsw)];
#pragma unroll
      for (int mi = 0; mi < 4; mi++)
#pragma unroll
        for (int ni = 0; ni < 4; ni++)
          acc[mi][ni] = __builtin_amdgcn_mfma_f32_16x16x32_bf16(
              af[mi], bfr[ni], acc[mi][ni], 0, 0, 0);
    }
    cur ^= 1;
  }

  if constexpr (OUT_BF16) {
    unsigned short* C = (unsigned short*)Cout + bz * cStride;
#pragma unroll
    for (int mi = 0; mi < 4; mi++)
#pragma unroll
      for (int ni = 0; ni < 4; ni++) {
        const int r0 = brow + wrow + mi * 16 + quad * 4;
        const int c = bcol + wcol + ni * 16 + l16;
#pragma unroll
        for (int r = 0; r < 4; r++)
          C[(long long)(r0 + r) * ldc + c] = f2bf(acc[mi][ni][r]);
      }
  } else {
    const float bv = bias[0];
    float* C = (float*)Cout + bz * cStride;
#pragma unroll
    for (int mi = 0; mi < 4; mi++)
#pragma unroll
      for (int ni = 0; ni < 4; ni++) {
        const int r0 = brow + wrow + mi * 16 + quad * 4;
        const int c = bcol + wcol + ni * 16 + l16;
#pragma unroll
        for (int r = 0; r < 4; r++)
          C[(long long)(r0 + r) * ldc + c] = acc[mi][ni][r] + bv;
      }
  }
}

extern "C" void kernel_launch(void* const* d_in, const int* in_sizes, int n_in,
                              void* d_out, int out_size, void* d_ws, size_t ws_size,
                              hipStream_t stream) {
  const float* t0 = (const float*)d_in[0];    // [8,2048,256]
  const float* t1 = (const float*)d_in[1];    // [8,2048,256]
  const float* kk = (const float*)d_in[2];    // [256,256]
  const float* bias = (const float*)d_in[3];  // [1]

  // ws layout (bf16 elements): T1b 4M | Qb 4M = 16.8 MiB
  unsigned short* T1b = (unsigned short*)d_ws;
  unsigned short* Qb = T1b + 4194304;

  // prep: blocks 0..255 gemm1 (Q = t0 . K^T, fp32-in bf16-out);
  //       blocks 256..1279 convert t1 -> bf16 on otherwise-idle CUs.
  prep<<<1280, 256, 0, stream>>>(t0, (const float4*)t1, kk, (ushort4*)T1b, Qb);

  // out[s][i][j] = sum_d t1[s,i,d]*Q[s,j,d] + bias : per-s 2048x2048, K=256
  gemm_nt<false><<<dim3(16, 16, 8), 256, 0, stream>>>(
      T1b, Qb, d_out, bias, 256, 2048, 524288LL, 524288LL, 4194304LL);
}

// Round 3
// 180.235 us; speedup vs baseline: 1.0317x; 1.0001x over previous
//
#include <hip/hip_runtime.h>
#include <hip/hip_bf16.h>

// Bilinear: out[s,i,j] = sum_{d,e} t1[s,i,d] * K[d,e] * t0[s,j,e] + bias
// S=8, N=2048, D=256.
// R5: two launches.
//   prep (fused, unchanged from R4): blocks 0..255 = gemm1 Q = t0.K^T
//     (fp32-in reg-staged, bf16-out); blocks 256..1279 = t1 fp32->bf16.
//   gemm2: counted-vmcnt pipeline (T3+T4): 4x BK=32 LDS buffers, 3-deep
//     global_load_lds prefetch, raw s_barrier + s_waitcnt vmcnt(8) (never
//     drain to 0 mid-loop), fully unrolled 8-step K=256 loop, setprio(1)
//     around each 16-MFMA cluster (T5), XCD swizzle s = bid&7 so each XCD's
//     L2 holds one batch slice's A/B panels (2 MB < 4 MB).

typedef __bf16 bf16x8 __attribute__((ext_vector_type(8)));
typedef float f32x4 __attribute__((ext_vector_type(4)));

__device__ __forceinline__ unsigned short f2bf(float f) {
  union { __hip_bfloat16 h; unsigned short u; } v;
  v.h = __float2bfloat16(f);
  return v.u;
}

// load 8 fp32, convert, store 8 bf16 (16B) -> LDS as one ds_write_b128
__device__ __forceinline__ void cvt8_store(unsigned short* dst, const float* src) {
  float4 v0 = *(const float4*)src;
  float4 v1 = *(const float4*)(src + 4);
  union { unsigned short u[8]; uint4 q; } p;
  p.u[0] = f2bf(v0.x); p.u[1] = f2bf(v0.y); p.u[2] = f2bf(v0.z); p.u[3] = f2bf(v0.w);
  p.u[4] = f2bf(v1.x); p.u[5] = f2bf(v1.y); p.u[6] = f2bf(v1.z); p.u[7] = f2bf(v1.w);
  *(uint4*)dst = p.q;
}

// Fused prep: gemm1 (fp32-in, bf16-out) on blocks 0..255; t1 cvt on 256..1279.
__global__ __launch_bounds__(256, 2) void prep(
    const float* __restrict__ t0, const float4* __restrict__ t1,
    const float* __restrict__ kk, ushort4* __restrict__ T1b,
    unsigned short* __restrict__ Qb) {
  const int tid = threadIdx.x;

  if (blockIdx.x >= 256) {
    const int i0 = (blockIdx.x - 256) * 256 + tid;
#pragma unroll
    for (int it = 0; it < 4; it++) {
      const int j = i0 + it * 262144;
      float4 v = t1[j];
      T1b[j] = make_ushort4(f2bf(v.x), f2bf(v.y), f2bf(v.z), f2bf(v.w));
    }
    return;
  }

  // ---- gemm1: Q[m][n] = sum_k t0[m][k] * K[n][k], M=16384 N=256 K=256 ----
  __shared__ unsigned short sA[2][128 * 64];
  __shared__ unsigned short sB[2][128 * 64];

  const int wave = tid >> 6;
  const int lane = tid & 63;
  const int quad = lane >> 4;
  const int l16 = lane & 15;
  const int wrow = (wave >> 1) * 64;
  const int wcol = (wave & 1) * 64;
  const int rsw = (l16 & 7) * 8;  // read-side XOR swizzle (elements)

  const int brow = (blockIdx.x >> 1) * 128;
  const int bcol = (blockIdx.x & 1) * 128;

  const float* Af = t0 + (long long)brow * 256;
  const float* Bf = kk + (long long)bcol * 256;

  const int srow = lane >> 3;                // row within 8-row group
  const int scol = ((lane & 7) ^ srow) * 8;  // pre-swizzled source col (elems)

  auto stage1 = [&](unsigned short* dA, unsigned short* dB, int kt) {
#pragma unroll
    for (int i = 0; i < 4; i++) {
      const int rr = i * 32 + wave * 8 + srow;
      cvt8_store(dA + rr * 64 + (lane & 7) * 8,
                 Af + (long long)rr * 256 + kt + scol);
      cvt8_store(dB + rr * 64 + (lane & 7) * 8,
                 Bf + (long long)rr * 256 + kt + scol);
    }
  };

  f32x4 acc[4][4];
#pragma unroll
  for (int i = 0; i < 4; i++)
#pragma unroll
    for (int j = 0; j < 4; j++) acc[i][j] = (f32x4){0.f, 0.f, 0.f, 0.f};

  stage1(sA[0], sB[0], 0);

  int cur = 0;
  for (int kt = 0; kt < 256; kt += 64) {
    __syncthreads();
    const unsigned short* a = sA[cur];
    const unsigned short* b = sB[cur];
    bf16x8 af[4], bfr[4];
#pragma unroll
    for (int mi = 0; mi < 4; mi++)
      af[mi] = *(const bf16x8*)&a[(wrow + mi * 16 + l16) * 64 + ((quad * 8) ^ rsw)];
#pragma unroll
    for (int ni = 0; ni < 4; ni++)
      bfr[ni] = *(const bf16x8*)&b[(wcol + ni * 16 + l16) * 64 + ((quad * 8) ^ rsw)];
    if (kt + 64 < 256) stage1(sA[cur ^ 1], sB[cur ^ 1], kt + 64);
#pragma unroll
    for (int mi = 0; mi < 4; mi++)
#pragma unroll
      for (int ni = 0; ni < 4; ni++)
        acc[mi][ni] = __builtin_amdgcn_mfma_f32_16x16x32_bf16(
            af[mi], bfr[ni], acc[mi][ni], 0, 0, 0);
#pragma unroll
    for (int mi = 0; mi < 4; mi++)
      af[mi] = *(const bf16x8*)&a[(wrow + mi * 16 + l16) * 64 + ((32 + quad * 8) ^ rsw)];
#pragma unroll
    for (int ni = 0; ni < 4; ni++)
      bfr[ni] = *(const bf16x8*)&b[(wcol + ni * 16 + l16) * 64 + ((32 + quad * 8) ^ rsw)];
#pragma unroll
    for (int mi = 0; mi < 4; mi++)
#pragma unroll
      for (int ni = 0; ni < 4; ni++)
        acc[mi][ni] = __builtin_amdgcn_mfma_f32_16x16x32_bf16(
            af[mi], bfr[ni], acc[mi][ni], 0, 0, 0);
    cur ^= 1;
  }

  // C/D frag mapping (m89-verified): col = lane&15, row = quad*4 + reg
#pragma unroll
  for (int mi = 0; mi < 4; mi++)
#pragma unroll
    for (int ni = 0; ni < 4; ni++) {
      const int r0 = brow + wrow + mi * 16 + quad * 4;
      const int c = bcol + wcol + ni * 16 + l16;
#pragma unroll
      for (int r = 0; r < 4; r++)
        Qb[(long long)(r0 + r) * 256 + c] = f2bf(acc[mi][ni][r]);
    }
}

// gemm2: out[s][i][j] = sum_d t1[s,i,d]*Q[s,j,d] + bias. K=256 hardcoded.
// 128x128 tile, 4 waves; 4x BK=32 buffers, 3-deep prefetch, counted vmcnt.
__global__ __launch_bounds__(256, 2) void gemm2(
    const unsigned short* __restrict__ A, const unsigned short* __restrict__ B,
    float* __restrict__ Cout, const float* __restrict__ bias) {
  __shared__ unsigned short sA[4][128 * 32];
  __shared__ unsigned short sB[4][128 * 32];

  const int tid = threadIdx.x;
  const int wave = tid >> 6;
  const int lane = tid & 63;
  const int quad = lane >> 4;
  const int l16 = lane & 15;
  const int wrow = (wave >> 1) * 64;
  const int wcol = (wave & 1) * 64;

  // XCD swizzle: consecutive HW block ids round-robin XCDs -> s = bid&7
  // pins one batch slice per XCD (A+B panels = 2 MB < 4 MB L2).
  const int bid = blockIdx.x;
  const long long s = bid & 7;
  const int t = bid >> 3;
  const int bcol = (t & 15) * 128;
  const int brow = (t >> 4) * 128;

  const unsigned short* Ab = A + s * 524288 + (long long)brow * 256;
  const unsigned short* Bb = B + s * 524288 + (long long)bcol * 256;

  // staging: lane -> (row = half*64 + wave*16 + lane/4, col = (lane&3)*8);
  // LDS dest wave-uniform base + lane*16B => linear row-major [128][32].
  // 64B row stride is bank-conflict-free for the b128 frag reads.
  const int srow = wave * 16 + (lane >> 2);
  const int scol = (lane & 3) * 8;

  auto stage = [&](unsigned short* dA, unsigned short* dB, int kt) {
#pragma unroll
    for (int half = 0; half < 2; half++) {
      const unsigned short* ga = Ab + (long long)(half * 64 + srow) * 256 + kt + scol;
      const unsigned short* gb = Bb + (long long)(half * 64 + srow) * 256 + kt + scol;
      __builtin_amdgcn_global_load_lds(
          (const __attribute__((address_space(1))) unsigned int*)ga,
          (__attribute__((address_space(3))) unsigned int*)(dA + (half * 64 + wave * 16) * 32),
          16, 0, 0);
      __builtin_amdgcn_global_load_lds(
          (const __attribute__((address_space(1))) unsigned int*)gb,
          (__attribute__((address_space(3))) unsigned int*)(dB + (half * 64 + wave * 16) * 32),
          16, 0, 0);
    }
  };

  f32x4 acc[4][4];
#pragma unroll
  for (int i = 0; i < 4; i++)
#pragma unroll
    for (int j = 0; j < 4; j++) acc[i][j] = (f32x4){0.f, 0.f, 0.f, 0.f};

  // 3-deep prologue: 12 loads/thread in flight.
  stage(sA[0], sB[0], 0);
  stage(sA[1], sB[1], 32);
  stage(sA[2], sB[2], 64);

  // Per step I (4 loads/thread per stage):
  //   wait vmcnt(VM): VM = 4 * (stages_issued_at_entry - (I+1));
  //   stages_issued_at_entry = 3 + min(I,5)  ->  VM = 8,8,8,8,8,8,4,0.
  //   barrier: all waves' buf[I&3] complete; all waves consumed step I-1
  //   ds_reads before crossing (lgkm-waited by their MFMAs), so staging
  //   buf[(I+3)&3] (last read at step I) after this barrier is race-free.
#define STEP(I, VM)                                                          \
  {                                                                          \
    asm volatile("s_waitcnt vmcnt(" #VM ")" ::: "memory");                   \
    __builtin_amdgcn_s_barrier();                                            \
    const unsigned short* a = sA[(I) & 3];                                   \
    const unsigned short* b = sB[(I) & 3];                                   \
    bf16x8 af[4], bfr[4];                                                    \
    _Pragma("unroll")                                                        \
    for (int mi = 0; mi < 4; mi++)                                           \
      af[mi] = *(const bf16x8*)&a[(wrow + mi * 16 + l16) * 32 + quad * 8];   \
    _Pragma("unroll")                                                        \
    for (int ni = 0; ni < 4; ni++)                                           \
      bfr[ni] = *(const bf16x8*)&b[(wcol + ni * 16 + l16) * 32 + quad * 8];  \
    if ((I) < 5) stage(sA[((I) + 3) & 3], sB[((I) + 3) & 3], ((I) + 3) * 32);\
    __builtin_amdgcn_s_setprio(1);                                           \
    _Pragma("unroll")                                                        \
    for (int mi = 0; mi < 4; mi++)                                           \
      _Pragma("unroll")                                                      \
      for (int ni = 0; ni < 4; ni++)                                         \
        acc[mi][ni] = __builtin_amdgcn_mfma_f32_16x16x32_bf16(               \
            af[mi], bfr[ni], acc[mi][ni], 0, 0, 0);                          \
    __builtin_amdgcn_s_setprio(0);                                           \
  }

  STEP(0, 8) STEP(1, 8) STEP(2, 8) STEP(3, 8)
  STEP(4, 8) STEP(5, 8) STEP(6, 4) STEP(7, 0)
#undef STEP

  // C/D frag mapping (m89-verified): col = lane&15, row = quad*4 + reg
  const float bv = bias[0];
  float* C = Cout + s * 4194304;
#pragma unroll
  for (int mi = 0; mi < 4; mi++)
#pragma unroll
    for (int ni = 0; ni < 4; ni++) {
      const int r0 = brow + wrow + mi * 16 + quad * 4;
      const int c = bcol + wcol + ni * 16 + l16;
#pragma unroll
      for (int r = 0; r < 4; r++)
        C[(long long)(r0 + r) * 2048 + c] = acc[mi][ni][r] + bv;
    }
}

extern "C" void kernel_launch(void* const* d_in, const int* in_sizes, int n_in,
                              void* d_out, int out_size, void* d_ws, size_t ws_size,
                              hipStream_t stream) {
  const float* t0 = (const float*)d_in[0];    // [8,2048,256]
  const float* t1 = (const float*)d_in[1];    // [8,2048,256]
  const float* kk = (const float*)d_in[2];    // [256,256]
  const float* bias = (const float*)d_in[3];  // [1]

  // ws layout (bf16 elements): T1b 4M | Qb 4M = 16.8 MiB
  unsigned short* T1b = (unsigned short*)d_ws;
  unsigned short* Qb = T1b + 4194304;

  // prep: blocks 0..255 gemm1 (Q = t0 . K^T, fp32-in bf16-out);
  //       blocks 256..1279 convert t1 -> bf16 on otherwise-idle CUs.
  prep<<<1280, 256, 0, stream>>>(t0, (const float4*)t1, kk, (ushort4*)T1b, Qb);

  // out[s][i][j] = sum_d t1[s,i,d]*Q[s,j,d] + bias : per-s 2048x2048, K=256
  gemm2<<<2048, 256, 0, stream>>>(T1b, Qb, (float*)d_out, bias);
}